// Round 12
// baseline (158.347 us; speedup 1.0000x reference)
//
#include <hip/hip_runtime.h>
#include <math.h>

// Single-head causal attention, B=8 T=2048 E=1024 D=64, fp32 in/out.
// wtrans (W -> bf16 W^T) -> qkv v3 (MFMA GEMM, global_load_lds staging of
// fp32 x, counted-vmcnt friendly issue order, 1 barrier/K-step) -> attn v2
// (flash attention, 32-row Q-strips, 8-wave blocks).

#define B_   8
#define T_   2048
#define E_   1024
#define D_   64
#define BT_  (B_ * T_)

typedef __attribute__((ext_vector_type(8))) short s16x8;   // 8 x bf16
typedef __attribute__((ext_vector_type(4))) short s16x4;
typedef __attribute__((ext_vector_type(4))) float f32x4;

__device__ __forceinline__ short f2bf(float f) {
    union { float f; unsigned u; } a; a.f = f;
    unsigned r = a.u + 0x7fffu + ((a.u >> 16) & 1u);   // RNE
    return (short)(r >> 16);
}

#define MFMA16(a, b, c) __builtin_amdgcn_mfma_f32_16x16x32_bf16((a), (b), (c), 0, 0, 0)

// async global->LDS DMA, 16B per lane. LDS dest is wave-uniform base +
// lane*16 (m104); global src is per-lane.
typedef __attribute__((address_space(1))) const unsigned int gu32;
typedef __attribute__((address_space(3)))       unsigned int su32;
__device__ __forceinline__ void gld16(const void* g, void* s) {
    __builtin_amdgcn_global_load_lds((gu32*)g, (su32*)s, 16, 0, 0);
}

// DPP cross-lane move within 16-lane rows (VALU pipe, not DS).
#define DPPF(x, ctrl) __builtin_bit_cast(float, \
    __builtin_amdgcn_update_dpp(0, __builtin_bit_cast(int, (x)), (ctrl), 0xF, 0xF, true))

__device__ __forceinline__ float rsum16(float x) {
    x += DPPF(x, 0xB1);     // quad_perm xor1
    x += DPPF(x, 0x4E);     // quad_perm xor2
    x += DPPF(x, 0x124);    // row_ror:4
    x += DPPF(x, 0x128);    // row_ror:8
    return x;
}

// ---------------------------------------------------------------------------
// Kernel 0: W[1024][64] x3 (fp32) -> Wt[192][1024] (bf16, K-major).
// ---------------------------------------------------------------------------
__global__ __launch_bounds__(256) void wtrans_kernel(
    const float* __restrict__ Wq, const float* __restrict__ Wk,
    const float* __restrict__ Wv, short* __restrict__ Wt)
{
    __shared__ float sT[64][65];
    const int sel = blockIdx.x >> 4;            // 0=q 1=k 2=v
    const int k0  = (blockIdx.x & 15) * 64;
    const float* W = sel == 0 ? Wq : (sel == 1 ? Wk : Wv);
    const int t  = threadIdx.x;
    const int kr = t >> 4, c4 = (t & 15) * 4;
    #pragma unroll
    for (int i = 0; i < 4; ++i) {
        float4 v = *(const float4*)&W[(size_t)(k0 + kr + i * 16) * D_ + c4];
        sT[kr + i * 16][c4 + 0] = v.x; sT[kr + i * 16][c4 + 1] = v.y;
        sT[kr + i * 16][c4 + 2] = v.z; sT[kr + i * 16][c4 + 3] = v.w;
    }
    __syncthreads();
    #pragma unroll
    for (int i = 0; i < 4; ++i) {
        int n  = (t >> 4) + i * 16;
        int kk = (t & 15) * 4;
        s16x4 o;
        o.x = f2bf(sT[kk + 0][n]); o.y = f2bf(sT[kk + 1][n]);
        o.z = f2bf(sT[kk + 2][n]); o.w = f2bf(sT[kk + 3][n]);
        *(s16x4*)&Wt[(size_t)(sel * 64 + n) * E_ + k0 + kk] = o;
    }
}

// ---------------------------------------------------------------------------
// Kernel 1: QKV projection v3. Block 512 = 8 waves, 64 tokens, grid 256
// (1 block/CU). BK=128, 8 K-steps. Staging: global_load_lds of fp32 x
// directly into LDS (linear [64][128] f32 per buffer, 32 wave-chunks of
// 1 KB). Per iteration: aw Wt loads issued FIRST (L2), then next-buffer
// gloads (counted vmcnt leaves them in flight through the MFMA body),
// fragments read fp32 from LDS + convert to bf16 in-register, 24 MFMA,
// ONE __syncthreads (its vmcnt drain now lands after a full body of cover).
// ---------------------------------------------------------------------------
__global__ __launch_bounds__(512) void qkv_kernel(
    const float* __restrict__ x, const short* __restrict__ Wt,
    const float* __restrict__ bq, const float* __restrict__ bk,
    const float* __restrict__ bv,
    short* __restrict__ Qg, short* __restrict__ Kg, short* __restrict__ VTg)
{
    __shared__ char sXm[2 * 64 * 128 * 4];      // [buf][64 tok][128 f32], 64 KB
    const int tid  = threadIdx.x;
    const int lane = tid & 63;
    const int w    = tid >> 6;                  // 0..7
    const int l15  = lane & 15, quad = lane >> 4;
    const int h2   = w & 1;                     // token half (2 tiles of 16)
    const int n2   = w >> 1;                    // 0..3 N-group (3 tiles each)
    const int t0   = blockIdx.x * 64;
    const int bb   = t0 >> 11;                  // batch (blocks don't straddle)

    // gload mapping: chunk cc = w*4+j (1 KB = 2 rows); lane covers
    // row 2cc+(lane>>5), cols (lane&31)*4 .. +3 (16 B).
    const int grow = lane >> 5;                 // 0/1 within chunk
    const int gcol = (lane & 31) << 2;          // 0..124

    f32x4 acc[3][2];
    #pragma unroll
    for (int a = 0; a < 3; ++a)
        #pragma unroll
        for (int h = 0; h < 2; ++h)
            acc[a][h] = (f32x4){0.f, 0.f, 0.f, 0.f};

    // prologue: stage k0=0 into buf 0
    #pragma unroll
    for (int j = 0; j < 4; ++j) {
        const int cc  = (w << 2) + j;
        const int row = (cc << 1) + grow;
        gld16(&x[(size_t)(t0 + row) * E_ + gcol], sXm + cc * 1024);
    }
    __syncthreads();                            // drain prologue stage

    int buf = 0;
    for (int k0 = 0; k0 < E_; k0 += 128) {
        // 1) Wt fragments first (L2-hot; MFMA's counted wait covers these)
        s16x8 aw[3][4];
        #pragma unroll
        for (int t3 = 0; t3 < 3; ++t3) {
            const short* pw = &Wt[(size_t)((n2 * 3 + t3) * 16 + l15) * E_ + k0 + quad * 8];
            #pragma unroll
            for (int kc = 0; kc < 4; ++kc)
                aw[t3][kc] = *(const s16x8*)(pw + kc * 32);
        }
        // 2) async stage of next K-slab into buf^1 (flies through the body)
        if (k0 + 128 < E_) {
            const char* dst = sXm + (buf ^ 1) * 32768;
            #pragma unroll
            for (int j = 0; j < 4; ++j) {
                const int cc  = (w << 2) + j;
                const int row = (cc << 1) + grow;
                gld16(&x[(size_t)(t0 + row) * E_ + k0 + 128 + gcol],
                      (void*)(dst + cc * 1024));
            }
        }
        // 3) x fragments: fp32 from LDS -> bf16 in-register
        s16x8 bxf[2][4];
        #pragma unroll
        for (int h = 0; h < 2; ++h) {
            const int trow = (h2 * 2 + h) * 16 + l15;
            const char* rb = sXm + buf * 32768 + trow * 512 + quad * 32;
            #pragma unroll
            for (int kc = 0; kc < 4; ++kc) {
                float4 xa = *(const float4*)(rb + kc * 128);
                float4 xb = *(const float4*)(rb + kc * 128 + 16);
                s16x8 f;
                f[0] = f2bf(xa.x); f[1] = f2bf(xa.y);
                f[2] = f2bf(xa.z); f[3] = f2bf(xa.w);
                f[4] = f2bf(xb.x); f[5] = f2bf(xb.y);
                f[6] = f2bf(xb.z); f[7] = f2bf(xb.w);
                bxf[h][kc] = f;
            }
        }
        // 4) MFMA
        #pragma unroll
        for (int t3 = 0; t3 < 3; ++t3)
            #pragma unroll
            for (int h = 0; h < 2; ++h)
                #pragma unroll
                for (int kc = 0; kc < 4; ++kc)
                    acc[t3][h] = MFMA16(aw[t3][kc], bxf[h][kc], acc[t3][h]);
        // 5) one barrier per K-step: drains gloads issued a full body ago
        __syncthreads();
        buf ^= 1;
    }

    short* sVT = (short*)sXm;                   // overlay: [64 feat][72 tok pad]

    #pragma unroll
    for (int t3 = 0; t3 < 3; ++t3) {
        const int nt = n2 * 3 + t3;
        const int fb = (nt & 3) * 16 + quad * 4;
        const float* bias = nt < 4 ? bq : (nt < 8 ? bk : bv);
        f32x4 bsv = *(const f32x4*)&bias[fb];
        #pragma unroll
        for (int h = 0; h < 2; ++h) {
            const int lt  = (h2 * 2 + h) * 16 + l15;
            const int tok = t0 + lt;
            f32x4 v = acc[t3][h] + bsv;
            if (nt < 4) {
                v *= 0.125f;                    // fold 1/sqrt(64) into Q
                s16x4 o = { f2bf(v[0]), f2bf(v[1]), f2bf(v[2]), f2bf(v[3]) };
                *(s16x4*)&Qg[(size_t)tok * D_ + fb] = o;
            } else if (nt < 8) {
                s16x4 o = { f2bf(v[0]), f2bf(v[1]), f2bf(v[2]), f2bf(v[3]) };
                *(s16x4*)&Kg[(size_t)tok * D_ + fb] = o;
            } else {
                #pragma unroll
                for (int r = 0; r < 4; ++r)
                    sVT[(fb + r) * 72 + lt] = f2bf(v[r]);
            }
        }
    }
    __syncthreads();
    {   // cooperative transposed V store: 64 features x 64 tokens, 16B/lane
        const int d  = tid >> 3;                // 0..63
        const int tq = (tid & 7) * 8;           // 0..56
        s16x8 vv = *(const s16x8*)&sVT[d * 72 + tq];
        *(s16x8*)&VTg[(size_t)(bb * D_ + d) * T_ + (t0 & (T_ - 1)) + tq] = vv;
    }
}

// ---------------------------------------------------------------------------
// Kernel 2: causal flash attention v2 — 32-row Q-strips (R10 WIN form).
// Each K/V chunk is loaded once and consumed by BOTH Q-tiles -> K/V L2
// traffic halved. 8 waves split the strip's chunks; merge = 8 partials.
// ---------------------------------------------------------------------------
__global__ __launch_bounds__(512) void attn_kernel(
    const short* __restrict__ Qg, const short* __restrict__ Kg,
    const short* __restrict__ VTg, float* __restrict__ out)
{
    __shared__ char smem[74752];
    short* sP = (short*)smem;                   // [8][2*16*72] bf16 (loop)
    float* sO = (float*)smem;                   // [8][64][36] fp32 (merge, union)
    float* sl = (float*)(smem + 73728);         // [8][32]

    const int tid  = threadIdx.x;
    const int lane = tid & 63;
    const int w    = tid >> 6;                  // 0..7
    const int l15  = lane & 15, quad = lane >> 4;
    const int b    = blockIdx.x & 7;
    const int j    = blockIdx.x >> 3;           // 0..63
    const int tq   = j * 32;
    const int nch  = (j >> 1) + 1;
    const int c0   = (w * nch) >> 3;
    const int c1   = ((w + 1) * nch) >> 3;

    // Q fragments: 2 tiles x 2 halves (pre-scaled by 1/8 in qkv)
    s16x8 aq[2][2];
    #pragma unroll
    for (int qt = 0; qt < 2; ++qt) {
        const size_t qoff = ((size_t)b * T_ + tq + qt * 16 + l15) * D_ + quad * 8;
        aq[qt][0] = *(const s16x8*)&Qg[qoff];
        aq[qt][1] = *(const s16x8*)&Qg[qoff + 32];
    }

    f32x4 oo[2][4];
    float lp[2][4];
    #pragma unroll
    for (int qt = 0; qt < 2; ++qt) {
        #pragma unroll
        for (int nt = 0; nt < 4; ++nt)
            oo[qt][nt] = (f32x4){0.f, 0.f, 0.f, 0.f};
        #pragma unroll
        for (int r = 0; r < 4; ++r) lp[qt][r] = 0.f;
    }

    const short* kb = Kg  + (size_t)b * T_ * D_;
    const short* vb = VTg + (size_t)b * D_ * T_;
    short* sPw = sP + w * (2 * 16 * 72);

    for (int cc = c0; cc < c1; ++cc) {
        const int s0 = cc * 64;
        s16x8 bk[4][2];
        #pragma unroll
        for (int nt = 0; nt < 4; ++nt) {
            const short* pk = kb + (size_t)(s0 + nt * 16 + l15) * D_ + quad * 8;
            bk[nt][0] = *(const s16x8*)pk;
            bk[nt][1] = *(const s16x8*)(pk + 32);
        }
        const f32x4 zz = (f32x4){0.f, 0.f, 0.f, 0.f};
        f32x4 sacc[2][4];
        #pragma unroll
        for (int qt = 0; qt < 2; ++qt)
            #pragma unroll
            for (int nt = 0; nt < 4; ++nt) {
                sacc[qt][nt] = MFMA16(aq[qt][0], bk[nt][0], zz);
                sacc[qt][nt] = MFMA16(aq[qt][1], bk[nt][1], sacc[qt][nt]);
            }
        s16x8 bv[4][2];
        #pragma unroll
        for (int nt = 0; nt < 4; ++nt) {
            const short* pv = vb + (size_t)(nt * 16 + l15) * T_ + s0 + quad * 8;
            bv[nt][0] = *(const s16x8*)pv;
            bv[nt][1] = *(const s16x8*)(pv + 32);
        }
        const bool diag = (cc == nch - 1);
        float p[2][4][4];
        #pragma unroll
        for (int qt = 0; qt < 2; ++qt)
            #pragma unroll
            for (int nt = 0; nt < 4; ++nt)
                #pragma unroll
                for (int r = 0; r < 4; ++r) {
                    float e = __expf(sacc[qt][nt][r]);
                    if (diag && (s0 + nt * 16 + l15 > tq + qt * 16 + quad * 4 + r))
                        e = 0.f;
                    p[qt][nt][r] = e;
                }
        #pragma unroll
        for (int qt = 0; qt < 2; ++qt)
            #pragma unroll
            for (int r = 0; r < 4; ++r)
                lp[qt][r] += (p[qt][0][r] + p[qt][1][r]) + (p[qt][2][r] + p[qt][3][r]);
        #pragma unroll
        for (int qt = 0; qt < 2; ++qt)
            #pragma unroll
            for (int nt = 0; nt < 4; ++nt)
                #pragma unroll
                for (int r = 0; r < 4; ++r)
                    sPw[qt * (16 * 72) + (quad * 4 + r) * 72 + nt * 16 + l15] =
                        f2bf(p[qt][nt][r]);
        #pragma unroll
        for (int qt = 0; qt < 2; ++qt) {
            s16x8 ap0 = *(const s16x8*)&sPw[qt * (16 * 72) + l15 * 72 + quad * 8];
            s16x8 ap1 = *(const s16x8*)&sPw[qt * (16 * 72) + l15 * 72 + 32 + quad * 8];
            #pragma unroll
            for (int nt = 0; nt < 4; ++nt) {
                oo[qt][nt] = MFMA16(ap0, bv[nt][0], oo[qt][nt]);
                oo[qt][nt] = MFMA16(ap1, bv[nt][1], oo[qt][nt]);
            }
        }
    }

    f32x4 lv[2];
    #pragma unroll
    for (int qt = 0; qt < 2; ++qt)
        #pragma unroll
        for (int r = 0; r < 4; ++r)
            lv[qt][r] = rsum16(lp[qt][r]);

    // ---- merge: 8 partials x 32 rows
    __syncthreads();                            // all waves done with sP
    {
        float* sOw = sO + w * (64 * 36);
        #pragma unroll
        for (int qt = 0; qt < 2; ++qt)
            #pragma unroll
            for (int nt = 0; nt < 4; ++nt)
                *(f32x4*)&sOw[(nt * 16 + l15) * 36 + qt * 16 + quad * 4] = oo[qt][nt];
        if (l15 == 0) {
            *(f32x4*)&sl[w * 32 + quad * 4]      = lv[0];
            *(f32x4*)&sl[w * 32 + 16 + quad * 4] = lv[1];
        }
    }
    __syncthreads();
    {
        const int d  = tid & 63;
        const int rb = (tid >> 6) * 4;          // 8 waves x 4 rows = 32
        f32x4 osum = (f32x4){0.f, 0.f, 0.f, 0.f};
        f32x4 lsum = (f32x4){0.f, 0.f, 0.f, 0.f};
        #pragma unroll
        for (int w2 = 0; w2 < 8; ++w2) {
            osum += *(const f32x4*)&sO[w2 * (64 * 36) + d * 36 + rb];
            lsum += *(const f32x4*)&sl[w2 * 32 + rb];
        }
        #pragma unroll
        for (int i = 0; i < 4; ++i)
            out[((size_t)b * T_ + tq + rb + i) * D_ + d] = osum[i] / lsum[i];
    }
}

extern "C" void kernel_launch(void* const* d_in, const int* in_sizes, int n_in,
                              void* d_out, int out_size, void* d_ws, size_t ws_size,
                              hipStream_t stream) {
    (void)in_sizes; (void)n_in; (void)out_size; (void)ws_size;
    const float* x  = (const float*)d_in[0];
    const float* Wq = (const float*)d_in[1];
    const float* bq = (const float*)d_in[2];
    const float* Wk = (const float*)d_in[3];
    const float* bk = (const float*)d_in[4];
    const float* Wv = (const float*)d_in[5];
    const float* bv = (const float*)d_in[6];

    char* ws = (char*)d_ws;
    short* Qg  = (short*)(ws);                           // [BT][64] bf16, 2 MB
    short* Kg  = (short*)(ws + (size_t)2 * 1024 * 1024);
    short* VTg = (short*)(ws + (size_t)4 * 1024 * 1024); // [B][64][T] bf16
    short* Wt  = (short*)(ws + (size_t)6 * 1024 * 1024); // [192][1024] bf16

    wtrans_kernel<<<48, 256, 0, stream>>>(Wq, Wk, Wv, Wt);
    qkv_kernel<<<BT_ / 64, 512, 0, stream>>>(x, Wt, bq, bk, bv, Qg, Kg, VTg);
    attn_kernel<<<B_ * 64, 512, 0, stream>>>(Qg, Kg, VTg, (float*)d_out);
}

// Round 13
// 141.120 us; speedup vs baseline: 1.1221x; 1.1221x over previous
//
#include <hip/hip_runtime.h>
#include <math.h>

// Single-head causal attention, B=8 T=2048 E=1024 D=64, fp32 in/out.
// wtrans (W -> bf16 W^T) -> qkv v4 (MFMA GEMM; Wt staged ONCE per block via
// global_load_lds with XOR-swizzled source -> issued L2 traffic 128->80 KB
// per CU per K-step; x via proven reg path) -> attn v2 (32-row Q-strips).

#define B_   8
#define T_   2048
#define E_   1024
#define D_   64
#define BT_  (B_ * T_)

typedef __attribute__((ext_vector_type(8))) short s16x8;   // 8 x bf16
typedef __attribute__((ext_vector_type(4))) short s16x4;
typedef __attribute__((ext_vector_type(4))) float f32x4;

__device__ __forceinline__ short f2bf(float f) {
    union { float f; unsigned u; } a; a.f = f;
    unsigned r = a.u + 0x7fffu + ((a.u >> 16) & 1u);   // RNE
    return (short)(r >> 16);
}

#define MFMA16(a, b, c) __builtin_amdgcn_mfma_f32_16x16x32_bf16((a), (b), (c), 0, 0, 0)

// async global->LDS DMA, 16B/lane; LDS dest = wave-uniform base + lane*16.
typedef __attribute__((address_space(1))) const unsigned int gu32;
typedef __attribute__((address_space(3)))       unsigned int su32;
__device__ __forceinline__ void gld16(const void* g, void* s) {
    __builtin_amdgcn_global_load_lds((gu32*)g, (su32*)s, 16, 0, 0);
}

// DPP cross-lane move within 16-lane rows (VALU pipe, not DS).
#define DPPF(x, ctrl) __builtin_bit_cast(float, \
    __builtin_amdgcn_update_dpp(0, __builtin_bit_cast(int, (x)), (ctrl), 0xF, 0xF, true))

__device__ __forceinline__ float rsum16(float x) {
    x += DPPF(x, 0xB1);     // quad_perm xor1
    x += DPPF(x, 0x4E);     // quad_perm xor2
    x += DPPF(x, 0x124);    // row_ror:4
    x += DPPF(x, 0x128);    // row_ror:8
    return x;
}

// ---------------------------------------------------------------------------
// Kernel 0: W[1024][64] x3 (fp32) -> Wt[192][1024] (bf16, K-major).
// ---------------------------------------------------------------------------
__global__ __launch_bounds__(256) void wtrans_kernel(
    const float* __restrict__ Wq, const float* __restrict__ Wk,
    const float* __restrict__ Wv, short* __restrict__ Wt)
{
    __shared__ float sT[64][65];
    const int sel = blockIdx.x >> 4;            // 0=q 1=k 2=v
    const int k0  = (blockIdx.x & 15) * 64;
    const float* W = sel == 0 ? Wq : (sel == 1 ? Wk : Wv);
    const int t  = threadIdx.x;
    const int kr = t >> 4, c4 = (t & 15) * 4;
    #pragma unroll
    for (int i = 0; i < 4; ++i) {
        float4 v = *(const float4*)&W[(size_t)(k0 + kr + i * 16) * D_ + c4];
        sT[kr + i * 16][c4 + 0] = v.x; sT[kr + i * 16][c4 + 1] = v.y;
        sT[kr + i * 16][c4 + 2] = v.z; sT[kr + i * 16][c4 + 3] = v.w;
    }
    __syncthreads();
    #pragma unroll
    for (int i = 0; i < 4; ++i) {
        int n  = (t >> 4) + i * 16;
        int kk = (t & 15) * 4;
        s16x4 o;
        o.x = f2bf(sT[kk + 0][n]); o.y = f2bf(sT[kk + 1][n]);
        o.z = f2bf(sT[kk + 2][n]); o.w = f2bf(sT[kk + 3][n]);
        *(s16x4*)&Wt[(size_t)(sel * 64 + n) * E_ + k0 + kk] = o;
    }
}

// ---------------------------------------------------------------------------
// Kernel 1: QKV projection v4. Block 512 = 8 waves, 64 tokens, grid 256.
// BK=128, 8 K-steps. Wt staged ONCE per block per K-step into LDS sW via
// gld16 (6 chunks/wave, double-buffered; source address XOR-pre-swizzled
// col16 ^= row&7 so linear LDS + swizzled ds_read is 2-way conflict-free).
// Issue order: x write -> barrier (drains prev-issued Wt glds, which had a
// full body to fly) -> issue Wt(k+1) glds -> ds_read fragments -> MFMA.
// x via v2 register path (140-short pad, conflict-clean). Issued traffic:
// 80 KB/CU/K-step (was 128: wave pairs duplicated Wt loads).
// ---------------------------------------------------------------------------
__global__ __launch_bounds__(512) void qkv_kernel(
    const float* __restrict__ x, const short* __restrict__ Wt,
    const float* __restrict__ bq, const float* __restrict__ bk,
    const float* __restrict__ bv,
    short* __restrict__ Qg, short* __restrict__ Kg, short* __restrict__ VTg)
{
    __shared__ short sW[2][12 * 16 * 128];      // 96 KB, linear rows 256 B
    __shared__ short sX[2][64 * 140];           // 35 KB, [tok][128+12 pad]
    const int tid  = threadIdx.x;
    const int lane = tid & 63;
    const int w    = tid >> 6;                  // 0..7
    const int l15  = lane & 15, quad = lane >> 4;
    const int h2   = w & 1;                     // token half (2 tiles of 16)
    const int n2   = w >> 1;                    // 0..3 N-group (3 tiles each)
    const int t0   = blockIdx.x * 64;
    const int bb   = t0 >> 11;                  // batch (blocks don't straddle)

    const int srow = tid >> 3;                  // 0..63
    const int skc  = (tid & 7) * 16;            // 0..112
    const float* px = &x[(size_t)(t0 + srow) * E_ + skc];

    // Wt gld16 mapping: chunk cid = w*6+j covers global rows
    // t3g*16 + rr (rr = (cid&3)*4 + lane>>4), 16 B units col16 = lane&15,
    // source pre-swizzled: col16s = (lane&15) ^ (rr&7).
    const int lrow = lane >> 4;                 // 0..3 within chunk
    const int lc16 = lane & 15;

    f32x4 acc[3][2];
    #pragma unroll
    for (int a = 0; a < 3; ++a)
        #pragma unroll
        for (int h = 0; h < 2; ++h)
            acc[a][h] = (f32x4){0.f, 0.f, 0.f, 0.f};

    float4 lda0 = *(const float4*)(px +   0);         // k0 = 0
    float4 lda1 = *(const float4*)(px +   4);
    float4 lda2 = *(const float4*)(px +   8);
    float4 lda3 = *(const float4*)(px +  12);
    float4 ldb0 = *(const float4*)(px + 128);         // k0 = 128
    float4 ldb1 = *(const float4*)(px + 132);
    float4 ldb2 = *(const float4*)(px + 136);
    float4 ldb3 = *(const float4*)(px + 140);

    // prologue: stage Wt(k0=0) into sW[0]
    #pragma unroll
    for (int j = 0; j < 6; ++j) {
        const int cid = w * 6 + j;
        const int t3g = cid >> 2;
        const int rr  = ((cid & 3) << 2) + lrow;
        const int c16 = lc16 ^ (rr & 7);
        gld16(&Wt[(size_t)(t3g * 16 + rr) * E_ + c16 * 8],
              (char*)&sW[0][0] + cid * 1024);
    }

    int buf = 0;
    for (int k0 = 0; k0 < E_; k0 += 128) {
        s16x8 pk0, pk1;
        pk0[0] = f2bf(lda0.x); pk0[1] = f2bf(lda0.y);
        pk0[2] = f2bf(lda0.z); pk0[3] = f2bf(lda0.w);
        pk0[4] = f2bf(lda1.x); pk0[5] = f2bf(lda1.y);
        pk0[6] = f2bf(lda1.z); pk0[7] = f2bf(lda1.w);
        pk1[0] = f2bf(lda2.x); pk1[1] = f2bf(lda2.y);
        pk1[2] = f2bf(lda2.z); pk1[3] = f2bf(lda2.w);
        pk1[4] = f2bf(lda3.x); pk1[5] = f2bf(lda3.y);
        pk1[6] = f2bf(lda3.z); pk1[7] = f2bf(lda3.w);
        *(s16x8*)&sX[buf][srow * 140 + skc]     = pk0;
        *(s16x8*)&sX[buf][srow * 140 + skc + 8] = pk1;
        __syncthreads();   // drains x writes (lgkm) + Wt(k) glds (vmcnt,
                           // issued last iteration -> full body of cover)

        lda0 = ldb0; lda1 = ldb1; lda2 = ldb2; lda3 = ldb3;
        if (k0 + 256 < E_) {
            const float* p2 = px + k0 + 256;
            ldb0 = *(const float4*)(p2 +  0);
            ldb1 = *(const float4*)(p2 +  4);
            ldb2 = *(const float4*)(p2 +  8);
            ldb3 = *(const float4*)(p2 + 12);
        }
        if (k0 + 128 < E_) {                    // stage Wt(k+1) -> sW[buf^1]
            #pragma unroll
            for (int j = 0; j < 6; ++j) {
                const int cid = w * 6 + j;
                const int t3g = cid >> 2;
                const int rr  = ((cid & 3) << 2) + lrow;
                const int c16 = lc16 ^ (rr & 7);
                gld16(&Wt[(size_t)(t3g * 16 + rr) * E_ + k0 + 128 + c16 * 8],
                      (char*)&sW[buf ^ 1][0] + cid * 1024);
            }
        }

        // aw fragments from sW[buf], XOR-swizzled read (2-way, free)
        s16x8 aw[3][4];
        #pragma unroll
        for (int t3 = 0; t3 < 3; ++t3) {
            const int tb = (n2 * 3 + t3) * 2048 + l15 * 128;
            #pragma unroll
            for (int kc = 0; kc < 4; ++kc) {
                const int c16 = (kc * 4 + quad) ^ (l15 & 7);
                aw[t3][kc] = *(const s16x8*)&sW[buf][tb + c16 * 8];
            }
        }
        // bxf fragments from sX[buf] (v2 path)
        s16x8 bxf[2][4];
        #pragma unroll
        for (int h = 0; h < 2; ++h) {
            const int trow = (h2 * 2 + h) * 16 + l15;
            #pragma unroll
            for (int kc = 0; kc < 4; ++kc)
                bxf[h][kc] = *(const s16x8*)&sX[buf][trow * 140 + kc * 32 + quad * 8];
        }
        #pragma unroll
        for (int t3 = 0; t3 < 3; ++t3)
            #pragma unroll
            for (int h = 0; h < 2; ++h)
                #pragma unroll
                for (int kc = 0; kc < 4; ++kc)
                    acc[t3][h] = MFMA16(aw[t3][kc], bxf[h][kc], acc[t3][h]);
        buf ^= 1;
    }

    __syncthreads();                            // main-loop LDS reads done
    short* sVT = &sX[0][0];                     // overlay: [64 feat][72 tok pad]

    #pragma unroll
    for (int t3 = 0; t3 < 3; ++t3) {
        const int nt = n2 * 3 + t3;
        const int fb = (nt & 3) * 16 + quad * 4;
        const float* bias = nt < 4 ? bq : (nt < 8 ? bk : bv);
        f32x4 bsv = *(const f32x4*)&bias[fb];
        #pragma unroll
        for (int h = 0; h < 2; ++h) {
            const int lt  = (h2 * 2 + h) * 16 + l15;
            const int tok = t0 + lt;
            f32x4 v = acc[t3][h] + bsv;
            if (nt < 4) {
                v *= 0.125f;                    // fold 1/sqrt(64) into Q
                s16x4 o = { f2bf(v[0]), f2bf(v[1]), f2bf(v[2]), f2bf(v[3]) };
                *(s16x4*)&Qg[(size_t)tok * D_ + fb] = o;
            } else if (nt < 8) {
                s16x4 o = { f2bf(v[0]), f2bf(v[1]), f2bf(v[2]), f2bf(v[3]) };
                *(s16x4*)&Kg[(size_t)tok * D_ + fb] = o;
            } else {
                #pragma unroll
                for (int r = 0; r < 4; ++r)
                    sVT[(fb + r) * 72 + lt] = f2bf(v[r]);
            }
        }
    }
    __syncthreads();
    {   // cooperative transposed V store: 64 features x 64 tokens, 16B/lane
        const int d  = tid >> 3;                // 0..63
        const int tq = (tid & 7) * 8;           // 0..56
        s16x8 vv = *(const s16x8*)&sVT[d * 72 + tq];
        *(s16x8*)&VTg[(size_t)(bb * D_ + d) * T_ + (t0 & (T_ - 1)) + tq] = vv;
    }
}

// ---------------------------------------------------------------------------
// Kernel 2: causal flash attention v2 — 32-row Q-strips (R10 WIN form).
// Each K/V chunk is loaded once and consumed by BOTH Q-tiles -> K/V L2
// traffic halved. 8 waves split the strip's chunks; merge = 8 partials.
// ---------------------------------------------------------------------------
__global__ __launch_bounds__(512) void attn_kernel(
    const short* __restrict__ Qg, const short* __restrict__ Kg,
    const short* __restrict__ VTg, float* __restrict__ out)
{
    __shared__ char smem[74752];
    short* sP = (short*)smem;                   // [8][2*16*72] bf16 (loop)
    float* sO = (float*)smem;                   // [8][64][36] fp32 (merge, union)
    float* sl = (float*)(smem + 73728);         // [8][32]

    const int tid  = threadIdx.x;
    const int lane = tid & 63;
    const int w    = tid >> 6;                  // 0..7
    const int l15  = lane & 15, quad = lane >> 4;
    const int b    = blockIdx.x & 7;
    const int j    = blockIdx.x >> 3;           // 0..63
    const int tq   = j * 32;
    const int nch  = (j >> 1) + 1;
    const int c0   = (w * nch) >> 3;
    const int c1   = ((w + 1) * nch) >> 3;

    // Q fragments: 2 tiles x 2 halves (pre-scaled by 1/8 in qkv)
    s16x8 aq[2][2];
    #pragma unroll
    for (int qt = 0; qt < 2; ++qt) {
        const size_t qoff = ((size_t)b * T_ + tq + qt * 16 + l15) * D_ + quad * 8;
        aq[qt][0] = *(const s16x8*)&Qg[qoff];
        aq[qt][1] = *(const s16x8*)&Qg[qoff + 32];
    }

    f32x4 oo[2][4];
    float lp[2][4];
    #pragma unroll
    for (int qt = 0; qt < 2; ++qt) {
        #pragma unroll
        for (int nt = 0; nt < 4; ++nt)
            oo[qt][nt] = (f32x4){0.f, 0.f, 0.f, 0.f};
        #pragma unroll
        for (int r = 0; r < 4; ++r) lp[qt][r] = 0.f;
    }

    const short* kb = Kg  + (size_t)b * T_ * D_;
    const short* vb = VTg + (size_t)b * D_ * T_;
    short* sPw = sP + w * (2 * 16 * 72);

    for (int cc = c0; cc < c1; ++cc) {
        const int s0 = cc * 64;
        s16x8 bk[4][2];
        #pragma unroll
        for (int nt = 0; nt < 4; ++nt) {
            const short* pk = kb + (size_t)(s0 + nt * 16 + l15) * D_ + quad * 8;
            bk[nt][0] = *(const s16x8*)pk;
            bk[nt][1] = *(const s16x8*)(pk + 32);
        }
        const f32x4 zz = (f32x4){0.f, 0.f, 0.f, 0.f};
        f32x4 sacc[2][4];
        #pragma unroll
        for (int qt = 0; qt < 2; ++qt)
            #pragma unroll
            for (int nt = 0; nt < 4; ++nt) {
                sacc[qt][nt] = MFMA16(aq[qt][0], bk[nt][0], zz);
                sacc[qt][nt] = MFMA16(aq[qt][1], bk[nt][1], sacc[qt][nt]);
            }
        s16x8 bv[4][2];
        #pragma unroll
        for (int nt = 0; nt < 4; ++nt) {
            const short* pv = vb + (size_t)(nt * 16 + l15) * T_ + s0 + quad * 8;
            bv[nt][0] = *(const s16x8*)pv;
            bv[nt][1] = *(const s16x8*)(pv + 32);
        }
        const bool diag = (cc == nch - 1);
        float p[2][4][4];
        #pragma unroll
        for (int qt = 0; qt < 2; ++qt)
            #pragma unroll
            for (int nt = 0; nt < 4; ++nt)
                #pragma unroll
                for (int r = 0; r < 4; ++r) {
                    float e = __expf(sacc[qt][nt][r]);
                    if (diag && (s0 + nt * 16 + l15 > tq + qt * 16 + quad * 4 + r))
                        e = 0.f;
                    p[qt][nt][r] = e;
                }
        #pragma unroll
        for (int qt = 0; qt < 2; ++qt)
            #pragma unroll
            for (int r = 0; r < 4; ++r)
                lp[qt][r] += (p[qt][0][r] + p[qt][1][r]) + (p[qt][2][r] + p[qt][3][r]);
        #pragma unroll
        for (int qt = 0; qt < 2; ++qt)
            #pragma unroll
            for (int nt = 0; nt < 4; ++nt)
                #pragma unroll
                for (int r = 0; r < 4; ++r)
                    sPw[qt * (16 * 72) + (quad * 4 + r) * 72 + nt * 16 + l15] =
                        f2bf(p[qt][nt][r]);
        #pragma unroll
        for (int qt = 0; qt < 2; ++qt) {
            s16x8 ap0 = *(const s16x8*)&sPw[qt * (16 * 72) + l15 * 72 + quad * 8];
            s16x8 ap1 = *(const s16x8*)&sPw[qt * (16 * 72) + l15 * 72 + 32 + quad * 8];
            #pragma unroll
            for (int nt = 0; nt < 4; ++nt) {
                oo[qt][nt] = MFMA16(ap0, bv[nt][0], oo[qt][nt]);
                oo[qt][nt] = MFMA16(ap1, bv[nt][1], oo[qt][nt]);
            }
        }
    }

    f32x4 lv[2];
    #pragma unroll
    for (int qt = 0; qt < 2; ++qt)
        #pragma unroll
        for (int r = 0; r < 4; ++r)
            lv[qt][r] = rsum16(lp[qt][r]);

    // ---- merge: 8 partials x 32 rows
    __syncthreads();                            // all waves done with sP
    {
        float* sOw = sO + w * (64 * 36);
        #pragma unroll
        for (int qt = 0; qt < 2; ++qt)
            #pragma unroll
            for (int nt = 0; nt < 4; ++nt)
                *(f32x4*)&sOw[(nt * 16 + l15) * 36 + qt * 16 + quad * 4] = oo[qt][nt];
        if (l15 == 0) {
            *(f32x4*)&sl[w * 32 + quad * 4]      = lv[0];
            *(f32x4*)&sl[w * 32 + 16 + quad * 4] = lv[1];
        }
    }
    __syncthreads();
    {
        const int d  = tid & 63;
        const int rb = (tid >> 6) * 4;          // 8 waves x 4 rows = 32
        f32x4 osum = (f32x4){0.f, 0.f, 0.f, 0.f};
        f32x4 lsum = (f32x4){0.f, 0.f, 0.f, 0.f};
        #pragma unroll
        for (int w2 = 0; w2 < 8; ++w2) {
            osum += *(const f32x4*)&sO[w2 * (64 * 36) + d * 36 + rb];
            lsum += *(const f32x4*)&sl[w2 * 32 + rb];
        }
        #pragma unroll
        for (int i = 0; i < 4; ++i)
            out[((size_t)b * T_ + tq + rb + i) * D_ + d] = osum[i] / lsum[i];
    }
}

extern "C" void kernel_launch(void* const* d_in, const int* in_sizes, int n_in,
                              void* d_out, int out_size, void* d_ws, size_t ws_size,
                              hipStream_t stream) {
    (void)in_sizes; (void)n_in; (void)out_size; (void)ws_size;
    const float* x  = (const float*)d_in[0];
    const float* Wq = (const float*)d_in[1];
    const float* bq = (const float*)d_in[2];
    const float* Wk = (const float*)d_in[3];
    const float* bk = (const float*)d_in[4];
    const float* Wv = (const float*)d_in[5];
    const float* bv = (const float*)d_in[6];

    char* ws = (char*)d_ws;
    short* Qg  = (short*)(ws);                           // [BT][64] bf16, 2 MB
    short* Kg  = (short*)(ws + (size_t)2 * 1024 * 1024);
    short* VTg = (short*)(ws + (size_t)4 * 1024 * 1024); // [B][64][T] bf16
    short* Wt  = (short*)(ws + (size_t)6 * 1024 * 1024); // [192][1024] bf16

    wtrans_kernel<<<48, 256, 0, stream>>>(Wq, Wk, Wv, Wt);
    qkv_kernel<<<BT_ / 64, 512, 0, stream>>>(x, Wt, bq, bk, bv, Qg, Kg, VTg);
    attn_kernel<<<B_ * 64, 512, 0, stream>>>(Qg, Kg, VTg, (float*)d_out);
}

// Round 16
// 135.332 us; speedup vs baseline: 1.1701x; 1.0428x over previous
//
#include <hip/hip_runtime.h>
#include <math.h>

// Single-head causal attention, B=8 T=2048 E=1024 D=64, fp32 in/out.
// wtrans (W -> bf16 W^T) -> qkv v4 (Wt staged once/block via gld16, R13 WIN)
// -> attn v3 (64-row Q-strips: K/V chunk amortized over 4 Q-tiles ->
// issued traffic 528->264 KB/CU; grid 256 = 1 block/CU).

#define B_   8
#define T_   2048
#define E_   1024
#define D_   64
#define BT_  (B_ * T_)

typedef __attribute__((ext_vector_type(8))) short s16x8;   // 8 x bf16
typedef __attribute__((ext_vector_type(4))) short s16x4;
typedef __attribute__((ext_vector_type(4))) float f32x4;

__device__ __forceinline__ short f2bf(float f) {
    union { float f; unsigned u; } a; a.f = f;
    unsigned r = a.u + 0x7fffu + ((a.u >> 16) & 1u);   // RNE
    return (short)(r >> 16);
}

#define MFMA16(a, b, c) __builtin_amdgcn_mfma_f32_16x16x32_bf16((a), (b), (c), 0, 0, 0)

// async global->LDS DMA, 16B/lane; LDS dest = wave-uniform base + lane*16.
typedef __attribute__((address_space(1))) const unsigned int gu32;
typedef __attribute__((address_space(3)))       unsigned int su32;
__device__ __forceinline__ void gld16(const void* g, void* s) {
    __builtin_amdgcn_global_load_lds((gu32*)g, (su32*)s, 16, 0, 0);
}

// DPP cross-lane move within 16-lane rows (VALU pipe, not DS).
#define DPPF(x, ctrl) __builtin_bit_cast(float, \
    __builtin_amdgcn_update_dpp(0, __builtin_bit_cast(int, (x)), (ctrl), 0xF, 0xF, true))

__device__ __forceinline__ float rsum16(float x) {
    x += DPPF(x, 0xB1);     // quad_perm xor1
    x += DPPF(x, 0x4E);     // quad_perm xor2
    x += DPPF(x, 0x124);    // row_ror:4
    x += DPPF(x, 0x128);    // row_ror:8
    return x;
}

// ---------------------------------------------------------------------------
// Kernel 0: W[1024][64] x3 (fp32) -> Wt[192][1024] (bf16, K-major).
// ---------------------------------------------------------------------------
__global__ __launch_bounds__(256) void wtrans_kernel(
    const float* __restrict__ Wq, const float* __restrict__ Wk,
    const float* __restrict__ Wv, short* __restrict__ Wt)
{
    __shared__ float sT[64][65];
    const int sel = blockIdx.x >> 4;            // 0=q 1=k 2=v
    const int k0  = (blockIdx.x & 15) * 64;
    const float* W = sel == 0 ? Wq : (sel == 1 ? Wk : Wv);
    const int t  = threadIdx.x;
    const int kr = t >> 4, c4 = (t & 15) * 4;
    #pragma unroll
    for (int i = 0; i < 4; ++i) {
        float4 v = *(const float4*)&W[(size_t)(k0 + kr + i * 16) * D_ + c4];
        sT[kr + i * 16][c4 + 0] = v.x; sT[kr + i * 16][c4 + 1] = v.y;
        sT[kr + i * 16][c4 + 2] = v.z; sT[kr + i * 16][c4 + 3] = v.w;
    }
    __syncthreads();
    #pragma unroll
    for (int i = 0; i < 4; ++i) {
        int n  = (t >> 4) + i * 16;
        int kk = (t & 15) * 4;
        s16x4 o;
        o.x = f2bf(sT[kk + 0][n]); o.y = f2bf(sT[kk + 1][n]);
        o.z = f2bf(sT[kk + 2][n]); o.w = f2bf(sT[kk + 3][n]);
        *(s16x4*)&Wt[(size_t)(sel * 64 + n) * E_ + k0 + kk] = o;
    }
}

// ---------------------------------------------------------------------------
// Kernel 1: QKV projection v4 (R13 WIN form). Block 512 = 8 waves, 64 tok,
// grid 256. BK=128. Wt staged once/block/K-step via gld16 (XOR-pre-swizzled
// source, linear LDS, swizzled 2-way-free ds_read); x via reg path.
// ---------------------------------------------------------------------------
__global__ __launch_bounds__(512) void qkv_kernel(
    const float* __restrict__ x, const short* __restrict__ Wt,
    const float* __restrict__ bq, const float* __restrict__ bk,
    const float* __restrict__ bv,
    short* __restrict__ Qg, short* __restrict__ Kg, short* __restrict__ VTg)
{
    __shared__ short sW[2][12 * 16 * 128];      // 96 KB, linear rows 256 B
    __shared__ short sX[2][64 * 140];           // 35 KB, [tok][128+12 pad]
    const int tid  = threadIdx.x;
    const int lane = tid & 63;
    const int w    = tid >> 6;                  // 0..7
    const int l15  = lane & 15, quad = lane >> 4;
    const int h2   = w & 1;                     // token half (2 tiles of 16)
    const int n2   = w >> 1;                    // 0..3 N-group (3 tiles each)
    const int t0   = blockIdx.x * 64;
    const int bb   = t0 >> 11;                  // batch (blocks don't straddle)

    const int srow = tid >> 3;                  // 0..63
    const int skc  = (tid & 7) * 16;            // 0..112
    const float* px = &x[(size_t)(t0 + srow) * E_ + skc];

    const int lrow = lane >> 4;                 // 0..3 within chunk
    const int lc16 = lane & 15;

    f32x4 acc[3][2];
    #pragma unroll
    for (int a = 0; a < 3; ++a)
        #pragma unroll
        for (int h = 0; h < 2; ++h)
            acc[a][h] = (f32x4){0.f, 0.f, 0.f, 0.f};

    float4 lda0 = *(const float4*)(px +   0);         // k0 = 0
    float4 lda1 = *(const float4*)(px +   4);
    float4 lda2 = *(const float4*)(px +   8);
    float4 lda3 = *(const float4*)(px +  12);
    float4 ldb0 = *(const float4*)(px + 128);         // k0 = 128
    float4 ldb1 = *(const float4*)(px + 132);
    float4 ldb2 = *(const float4*)(px + 136);
    float4 ldb3 = *(const float4*)(px + 140);

    // prologue: stage Wt(k0=0) into sW[0]
    #pragma unroll
    for (int j = 0; j < 6; ++j) {
        const int cid = w * 6 + j;
        const int t3g = cid >> 2;
        const int rr  = ((cid & 3) << 2) + lrow;
        const int c16 = lc16 ^ (rr & 7);
        gld16(&Wt[(size_t)(t3g * 16 + rr) * E_ + c16 * 8],
              (char*)&sW[0][0] + cid * 1024);
    }

    int buf = 0;
    for (int k0 = 0; k0 < E_; k0 += 128) {
        s16x8 pk0, pk1;
        pk0[0] = f2bf(lda0.x); pk0[1] = f2bf(lda0.y);
        pk0[2] = f2bf(lda0.z); pk0[3] = f2bf(lda0.w);
        pk0[4] = f2bf(lda1.x); pk0[5] = f2bf(lda1.y);
        pk0[6] = f2bf(lda1.z); pk0[7] = f2bf(lda1.w);
        pk1[0] = f2bf(lda2.x); pk1[1] = f2bf(lda2.y);
        pk1[2] = f2bf(lda2.z); pk1[3] = f2bf(lda2.w);
        pk1[4] = f2bf(lda3.x); pk1[5] = f2bf(lda3.y);
        pk1[6] = f2bf(lda3.z); pk1[7] = f2bf(lda3.w);
        *(s16x8*)&sX[buf][srow * 140 + skc]     = pk0;
        *(s16x8*)&sX[buf][srow * 140 + skc + 8] = pk1;
        __syncthreads();   // drains x writes + Wt(k) glds (full body of cover)

        lda0 = ldb0; lda1 = ldb1; lda2 = ldb2; lda3 = ldb3;
        if (k0 + 256 < E_) {
            const float* p2 = px + k0 + 256;
            ldb0 = *(const float4*)(p2 +  0);
            ldb1 = *(const float4*)(p2 +  4);
            ldb2 = *(const float4*)(p2 +  8);
            ldb3 = *(const float4*)(p2 + 12);
        }
        if (k0 + 128 < E_) {                    // stage Wt(k+1) -> sW[buf^1]
            #pragma unroll
            for (int j = 0; j < 6; ++j) {
                const int cid = w * 6 + j;
                const int t3g = cid >> 2;
                const int rr  = ((cid & 3) << 2) + lrow;
                const int c16 = lc16 ^ (rr & 7);
                gld16(&Wt[(size_t)(t3g * 16 + rr) * E_ + k0 + 128 + c16 * 8],
                      (char*)&sW[buf ^ 1][0] + cid * 1024);
            }
        }

        s16x8 aw[3][4];
        #pragma unroll
        for (int t3 = 0; t3 < 3; ++t3) {
            const int tb = (n2 * 3 + t3) * 2048 + l15 * 128;
            #pragma unroll
            for (int kc = 0; kc < 4; ++kc) {
                const int c16 = (kc * 4 + quad) ^ (l15 & 7);
                aw[t3][kc] = *(const s16x8*)&sW[buf][tb + c16 * 8];
            }
        }
        s16x8 bxf[2][4];
        #pragma unroll
        for (int h = 0; h < 2; ++h) {
            const int trow = (h2 * 2 + h) * 16 + l15;
            #pragma unroll
            for (int kc = 0; kc < 4; ++kc)
                bxf[h][kc] = *(const s16x8*)&sX[buf][trow * 140 + kc * 32 + quad * 8];
        }
        #pragma unroll
        for (int t3 = 0; t3 < 3; ++t3)
            #pragma unroll
            for (int h = 0; h < 2; ++h)
                #pragma unroll
                for (int kc = 0; kc < 4; ++kc)
                    acc[t3][h] = MFMA16(aw[t3][kc], bxf[h][kc], acc[t3][h]);
        buf ^= 1;
    }

    __syncthreads();                            // main-loop LDS reads done
    short* sVT = &sX[0][0];                     // overlay: [64 feat][72 tok pad]

    #pragma unroll
    for (int t3 = 0; t3 < 3; ++t3) {
        const int nt = n2 * 3 + t3;
        const int fb = (nt & 3) * 16 + quad * 4;
        const float* bias = nt < 4 ? bq : (nt < 8 ? bk : bv);
        f32x4 bsv = *(const f32x4*)&bias[fb];
        #pragma unroll
        for (int h = 0; h < 2; ++h) {
            const int lt  = (h2 * 2 + h) * 16 + l15;
            const int tok = t0 + lt;
            f32x4 v = acc[t3][h] + bsv;
            if (nt < 4) {
                v *= 0.125f;                    // fold 1/sqrt(64) into Q
                s16x4 o = { f2bf(v[0]), f2bf(v[1]), f2bf(v[2]), f2bf(v[3]) };
                *(s16x4*)&Qg[(size_t)tok * D_ + fb] = o;
            } else if (nt < 8) {
                s16x4 o = { f2bf(v[0]), f2bf(v[1]), f2bf(v[2]), f2bf(v[3]) };
                *(s16x4*)&Kg[(size_t)tok * D_ + fb] = o;
            } else {
                #pragma unroll
                for (int r = 0; r < 4; ++r)
                    sVT[(fb + r) * 72 + lt] = f2bf(v[r]);
            }
        }
    }
    __syncthreads();
    {   // cooperative transposed V store: 64 features x 64 tokens, 16B/lane
        const int d  = tid >> 3;                // 0..63
        const int tq = (tid & 7) * 8;           // 0..56
        s16x8 vv = *(const s16x8*)&sVT[d * 72 + tq];
        *(s16x8*)&VTg[(size_t)(bb * D_ + d) * T_ + (t0 & (T_ - 1)) + tq] = vv;
    }
}

// ---------------------------------------------------------------------------
// Kernel 2: causal flash attention v3 — 64-row Q-strips (4 MFMA tiles).
// Block (b = blk&7, j = blk>>3, j=0..31): Q rows [j*64, j*64+64).
// Each K/V chunk is loaded once and consumed by FOUR Q-tiles -> issued
// traffic 264 KB/CU (was 528). 8 waves split the strip's nch=j+1 chunks.
// QK processes tiles sequentially (sacc/p reused, P dumped to LDS per
// tile, bk dead before bv loads) to bound VGPR. Merge: 8 partials x 64
// rows, LDS 138 KB, 1 block/CU.
// ---------------------------------------------------------------------------
__global__ __launch_bounds__(512) void attn_kernel(
    const short* __restrict__ Qg, const short* __restrict__ Kg,
    const short* __restrict__ VTg, float* __restrict__ out)
{
    __shared__ char smem[141312];
    short* sP = (short*)smem;                   // [8][4*16*72] bf16 (loop)
    float* sO = (float*)smem;                   // [8][64][68] fp32 (merge)
    float* sl = (float*)(smem + 139264);        // [8][64]

    const int tid  = threadIdx.x;
    const int lane = tid & 63;
    const int w    = tid >> 6;                  // 0..7
    const int l15  = lane & 15, quad = lane >> 4;
    const int b    = blockIdx.x & 7;
    const int j    = blockIdx.x >> 3;           // 0..31
    const int tq   = j * 64;
    const int nch  = j + 1;
    const int c0   = (w * nch) >> 3;
    const int c1   = ((w + 1) * nch) >> 3;

    // Q fragments: 4 tiles x 2 halves (pre-scaled by 1/8 in qkv)
    s16x8 aq[4][2];
    #pragma unroll
    for (int qt = 0; qt < 4; ++qt) {
        const size_t qoff = ((size_t)b * T_ + tq + qt * 16 + l15) * D_ + quad * 8;
        aq[qt][0] = *(const s16x8*)&Qg[qoff];
        aq[qt][1] = *(const s16x8*)&Qg[qoff + 32];
    }

    f32x4 oo[4][4];
    float lp[4][4];
    #pragma unroll
    for (int qt = 0; qt < 4; ++qt) {
        #pragma unroll
        for (int nt = 0; nt < 4; ++nt)
            oo[qt][nt] = (f32x4){0.f, 0.f, 0.f, 0.f};
        #pragma unroll
        for (int r = 0; r < 4; ++r) lp[qt][r] = 0.f;
    }

    const short* kb = Kg  + (size_t)b * T_ * D_;
    const short* vb = VTg + (size_t)b * D_ * T_;
    short* sPw = sP + w * (4 * 16 * 72);

    for (int cc = c0; cc < c1; ++cc) {
        const int s0 = cc * 64;
        const bool diag = (cc == nch - 1);
        // K fragments (dead before bv loads -> phase-disjoint registers)
        s16x8 bk[4][2];
        #pragma unroll
        for (int nt = 0; nt < 4; ++nt) {
            const short* pk = kb + (size_t)(s0 + nt * 16 + l15) * D_ + quad * 8;
            bk[nt][0] = *(const s16x8*)pk;
            bk[nt][1] = *(const s16x8*)(pk + 32);
        }
        const f32x4 zz = (f32x4){0.f, 0.f, 0.f, 0.f};
        // QK + softmax-partial per tile, P dumped to LDS (sacc/p reused)
        #pragma unroll
        for (int qt = 0; qt < 4; ++qt) {
            f32x4 sacc[4];
            #pragma unroll
            for (int nt = 0; nt < 4; ++nt) {
                sacc[nt] = MFMA16(aq[qt][0], bk[nt][0], zz);
                sacc[nt] = MFMA16(aq[qt][1], bk[nt][1], sacc[nt]);
            }
            float p[4][4];
            #pragma unroll
            for (int nt = 0; nt < 4; ++nt)
                #pragma unroll
                for (int r = 0; r < 4; ++r) {
                    float e = __expf(sacc[nt][r]);
                    if (diag && (s0 + nt * 16 + l15 > tq + qt * 16 + quad * 4 + r))
                        e = 0.f;
                    p[nt][r] = e;
                }
            #pragma unroll
            for (int r = 0; r < 4; ++r)
                lp[qt][r] += (p[0][r] + p[1][r]) + (p[2][r] + p[3][r]);
            #pragma unroll
            for (int nt = 0; nt < 4; ++nt)
                #pragma unroll
                for (int r = 0; r < 4; ++r)
                    sPw[qt * (16 * 72) + (quad * 4 + r) * 72 + nt * 16 + l15] =
                        f2bf(p[nt][r]);
        }
        // V fragments
        s16x8 bv[4][2];
        #pragma unroll
        for (int nt = 0; nt < 4; ++nt) {
            const short* pv = vb + (size_t)(nt * 16 + l15) * T_ + s0 + quad * 8;
            bv[nt][0] = *(const s16x8*)pv;
            bv[nt][1] = *(const s16x8*)(pv + 32);
        }
        // PV per tile
        #pragma unroll
        for (int qt = 0; qt < 4; ++qt) {
            s16x8 ap0 = *(const s16x8*)&sPw[qt * (16 * 72) + l15 * 72 + quad * 8];
            s16x8 ap1 = *(const s16x8*)&sPw[qt * (16 * 72) + l15 * 72 + 32 + quad * 8];
            #pragma unroll
            for (int nt = 0; nt < 4; ++nt) {
                oo[qt][nt] = MFMA16(ap0, bv[nt][0], oo[qt][nt]);
                oo[qt][nt] = MFMA16(ap1, bv[nt][1], oo[qt][nt]);
            }
        }
    }

    f32x4 lv[4];
    #pragma unroll
    for (int qt = 0; qt < 4; ++qt)
        #pragma unroll
        for (int r = 0; r < 4; ++r)
            lv[qt][r] = rsum16(lp[qt][r]);

    // ---- merge: 8 partials x 64 rows
    __syncthreads();                            // all waves done with sP
    {
        float* sOw = sO + w * (64 * 68);
        #pragma unroll
        for (int qt = 0; qt < 4; ++qt)
            #pragma unroll
            for (int nt = 0; nt < 4; ++nt)
                *(f32x4*)&sOw[(nt * 16 + l15) * 68 + qt * 16 + quad * 4] = oo[qt][nt];
        if (l15 == 0) {
            #pragma unroll
            for (int qt = 0; qt < 4; ++qt)
                *(f32x4*)&sl[w * 64 + qt * 16 + quad * 4] = lv[qt];
        }
    }
    __syncthreads();
    {
        const int d  = tid & 63;
        const int rb = (tid >> 6) * 8;          // 8 groups x 8 rows = 64
        f32x4 osum0 = (f32x4){0.f, 0.f, 0.f, 0.f};
        f32x4 osum1 = (f32x4){0.f, 0.f, 0.f, 0.f};
        f32x4 lsum0 = (f32x4){0.f, 0.f, 0.f, 0.f};
        f32x4 lsum1 = (f32x4){0.f, 0.f, 0.f, 0.f};
        #pragma unroll
        for (int w2 = 0; w2 < 8; ++w2) {
            const float* so  = &sO[w2 * (64 * 68) + d * 68 + rb];
            const float* slp = &sl[w2 * 64 + rb];
            osum0 += *(const f32x4*)(so);
            osum1 += *(const f32x4*)(so + 4);
            lsum0 += *(const f32x4*)(slp);
            lsum1 += *(const f32x4*)(slp + 4);
        }
        #pragma unroll
        for (int i = 0; i < 4; ++i)
            out[((size_t)b * T_ + tq + rb + i) * D_ + d] = osum0[i] / lsum0[i];
        #pragma unroll
        for (int i = 0; i < 4; ++i)
            out[((size_t)b * T_ + tq + rb + 4 + i) * D_ + d] = osum1[i] / lsum1[i];
    }
}

extern "C" void kernel_launch(void* const* d_in, const int* in_sizes, int n_in,
                              void* d_out, int out_size, void* d_ws, size_t ws_size,
                              hipStream_t stream) {
    (void)in_sizes; (void)n_in; (void)out_size; (void)ws_size;
    const float* x  = (const float*)d_in[0];
    const float* Wq = (const float*)d_in[1];
    const float* bq = (const float*)d_in[2];
    const float* Wk = (const float*)d_in[3];
    const float* bk = (const float*)d_in[4];
    const float* Wv = (const float*)d_in[5];
    const float* bv = (const float*)d_in[6];

    char* ws = (char*)d_ws;
    short* Qg  = (short*)(ws);                           // [BT][64] bf16, 2 MB
    short* Kg  = (short*)(ws + (size_t)2 * 1024 * 1024);
    short* VTg = (short*)(ws + (size_t)4 * 1024 * 1024); // [B][64][T] bf16
    short* Wt  = (short*)(ws + (size_t)6 * 1024 * 1024); // [192][1024] bf16

    wtrans_kernel<<<48, 256, 0, stream>>>(Wq, Wk, Wv, Wt);
    qkv_kernel<<<BT_ / 64, 512, 0, stream>>>(x, Wt, bq, bk, bv, Qg, Kg, VTg);
    attn_kernel<<<B_ * 32, 512, 0, stream>>>(Qg, Kg, VTg, (float*)d_out);
}